// Round 16
// baseline (321.569 us; speedup 1.0000x reference)
//
#include <hip/hip_runtime.h>
#include <stdint.h>

#define NROWS 262144
#define DDIM 128
#define NCLS 512
#define NHB 64  // hist/scatter blocks
constexpr float INV_BETA = 10.0f;
constexpr float EXP2_SCALE = 14.426950408889634f;  // 10 * log2(e)

typedef __bf16 v8bf __attribute__((ext_vector_type(8)));
typedef float v4f __attribute__((ext_vector_type(4)));

__device__ inline unsigned short f2bf(float f) {
    uint32_t u = __builtin_bit_cast(uint32_t, f);
    u += 0x7FFFu + ((u >> 16) & 1u);
    return (unsigned short)(u >> 16);
}
__device__ inline float bflo(uint32_t u) { return __builtin_bit_cast(float, u << 16); }
__device__ inline float bfhi(uint32_t u) { return __builtin_bit_cast(float, u & 0xFFFF0000u); }

#define GLL16(gsrc, ldst)                                                        \
    __builtin_amdgcn_global_load_lds(                                            \
        (const __attribute__((address_space(1))) void*)(uintptr_t)(gsrc),        \
        (__attribute__((address_space(3))) void*)(uintptr_t)(ldst), 16, 0, 0)

// K1 v5: streaming L2-normalize fp32 -> bf16 (blocks 0..8191); histogram fused.
__global__ __launch_bounds__(256) void k1_normalize(
    const float* __restrict__ in, const int* __restrict__ tgt,
    unsigned short* __restrict__ xb, int* __restrict__ bh) {
    __shared__ int h[NCLS];
    int t = threadIdx.x;
    if (blockIdx.x >= 8192) {
        int b = blockIdx.x - 8192;
        for (int i = t; i < NCLS; i += 256) h[i] = 0;
        __syncthreads();
        int base = b * (NROWS / NHB);
        for (int i = base + t; i < base + NROWS / NHB; i += 256)
            atomicAdd(&h[tgt[i]], 1);
        __syncthreads();
        for (int i = t; i < NCLS; i += 256)
            bh[b * NCLS + i] = h[i];
        return;
    }
    int w = t >> 6;
    int half = (t & 63) >> 5;
    int lane32 = t & 31;
    int hw = blockIdx.x * 8 + w * 2 + half;
    int r0 = hw * 4;
    float4 v[4];
#pragma unroll
    for (int j = 0; j < 4; ++j)
        v[j] = *reinterpret_cast<const float4*>(in + (size_t)(r0 + j) * DDIM + lane32 * 4);
    float s[4];
#pragma unroll
    for (int j = 0; j < 4; ++j)
        s[j] = v[j].x * v[j].x + v[j].y * v[j].y + v[j].z * v[j].z + v[j].w * v[j].w;
#pragma unroll
    for (int off = 1; off < 32; off <<= 1) {
#pragma unroll
        for (int j = 0; j < 4; ++j) s[j] += __shfl_xor(s[j], off);
    }
#pragma unroll
    for (int j = 0; j < 4; ++j) {
        float iv = rsqrtf(fmaxf(s[j], 1e-24f));
        ushort4 o;
        o.x = f2bf(v[j].x * iv); o.y = f2bf(v[j].y * iv);
        o.z = f2bf(v[j].z * iv); o.w = f2bf(v[j].w * iv);
        *reinterpret_cast<ushort4*>(xb + (size_t)(r0 + j) * DDIM + lane32 * 4) = o;
    }
}

__global__ __launch_bounds__(512) void k_prefix(
    const int* __restrict__ bh, int* __restrict__ counts, int* __restrict__ offs,
    int* __restrict__ base, float* __restrict__ nabsG, float* __restrict__ out) {
    __shared__ int sc[NCLS];
    __shared__ int za;
    int t = threadIdx.x;
    int cnt = 0;
#pragma unroll 8
    for (int b = 0; b < NHB; ++b) cnt += bh[b * NCLS + t];
    counts[t] = cnt;
    sc[t] = cnt;
    if (t == 0) za = 0;
    __syncthreads();
    for (int off = 1; off < NCLS; off <<= 1) {
        int v = (t >= off) ? sc[t - off] : 0;
        __syncthreads();
        sc[t] += v;
        __syncthreads();
    }
    int excl = sc[t] - cnt;
    offs[t] = excl;
    if (cnt == 0) atomicAdd(&za, 1);
    int run = excl;
    for (int b = 0; b < NHB; ++b) {
        base[b * NCLS + t] = run;
        run += bh[b * NCLS + t];
    }
    __syncthreads();
    if (t == 0) { *nabsG = (float)za; *out = 0.0f; }
}

__global__ __launch_bounds__(256) void k_scatter(
    const int* __restrict__ tgt, const int* __restrict__ base, int* __restrict__ ridx) {
    __shared__ int cur[NCLS];
    int t = threadIdx.x;
    int b = blockIdx.x;
    cur[t] = base[b * NCLS + t];
    cur[t + 256] = base[b * NCLS + t + 256];
    __syncthreads();
    int r0 = b * (NROWS / NHB);
    for (int i = t; i < NROWS / NHB; i += 256) {
        int row = r0 + i;
        int c = tgt[row];
        int pos = atomicAdd(&cur[c], 1);
        ridx[pos] = row;
    }
}

// centers gather body (MLP 16), shared by real kernel and probe.
__device__ inline void centers_gather(
    const uint32_t* __restrict__ xb32, const int* __restrict__ ridx,
    int start, int lo, int hi, int l, float& a0, float& a1) {
    int i = lo;
    for (; i + 16 <= hi; i += 16) {
        int id[16]; uint32_t v[16];
#pragma unroll
        for (int j = 0; j < 16; ++j) id[j] = ridx[start + i + j];
#pragma unroll
        for (int j = 0; j < 16; ++j) v[j] = xb32[(size_t)id[j] * 64 + l];
#pragma unroll
        for (int j = 0; j < 16; ++j) { a0 += bflo(v[j]); a1 += bfhi(v[j]); }
    }
    for (; i < hi; ++i) {
        uint32_t v = xb32[(size_t)ridx[start + i] * 64 + l];
        a0 += bflo(v); a1 += bfhi(v);
    }
}

// Per-class mean + L2-normalize -> bf16 centers pre-scaled by 10*log2(e).
__global__ __launch_bounds__(512) void k_centers(
    const unsigned short* __restrict__ xb, const int* __restrict__ ridx,
    const int* __restrict__ counts, const int* __restrict__ offs,
    unsigned short* __restrict__ cen, float* __restrict__ out) {
    __shared__ float2 sP[8][64];
    int t = threadIdx.x, w = t >> 6, l = t & 63;
    int cl = blockIdx.x;
    int cnt = counts[cl], start = offs[cl];
    float a0 = 0.0f, a1 = 0.0f;
    int per = (cnt + 7) >> 3;
    int lo = w * per, hi = min(cnt, lo + per);
    centers_gather((const uint32_t*)xb, ridx, start, lo, hi, l, a0, a1);
    sP[w][l] = make_float2(a0, a1);
    __syncthreads();
    if (w == 0) {
        float c0 = 0.0f, c1 = 0.0f;
#pragma unroll
        for (int q = 0; q < 8; ++q) { c0 += sP[q][l].x; c1 += sP[q][l].y; }
        float fc = fmaxf((float)cnt, 1.0f);
        c0 /= fc; c1 /= fc;
        float ss = c0 * c0 + c1 * c1;
        for (int off = 1; off < 64; off <<= 1) ss += __shfl_xor(ss, off);
        float inv = EXP2_SCALE / fmaxf(sqrtf(ss), 1e-12f);
        ushort2 o;
        o.x = f2bf(c0 * inv); o.y = f2bf(c1 * inv);
        *reinterpret_cast<ushort2*>(cen + (size_t)cl * DDIM + l * 2) = o;
        if (l == 0)
            atomicAdd(out, -(float)cnt * sqrtf(ss) * (INV_BETA / (float)NROWS));
    }
}

// PROBE: 4 cold gather sweeps (different class each rep) -> counters visible.
__global__ __launch_bounds__(512) void cen_probe(
    const unsigned short* __restrict__ xb, const int* __restrict__ ridx,
    const int* __restrict__ counts, const int* __restrict__ offs,
    unsigned short* __restrict__ cen2, float* __restrict__ out2) {
    __shared__ float2 sP[8][64];
    int t = threadIdx.x, w = t >> 6, l = t & 63;
    float a0 = 0.0f, a1 = 0.0f;
    int cntL = 1;
    for (int rep = 0; rep < 4; ++rep) {
        int cl = (blockIdx.x + rep * 128) & (NCLS - 1);
        int cnt = counts[cl], start = offs[cl];
        cntL = cnt;
        int per = (cnt + 7) >> 3;
        int lo = w * per, hi = min(cnt, lo + per);
        centers_gather((const uint32_t*)xb, ridx, start, lo, hi, l, a0, a1);
    }
    sP[w][l] = make_float2(a0, a1);
    __syncthreads();
    if (w == 0) {
        float c0 = 0.0f, c1 = 0.0f;
#pragma unroll
        for (int q = 0; q < 8; ++q) { c0 += sP[q][l].x; c1 += sP[q][l].y; }
        float fc = fmaxf((float)cntL, 1.0f);
        c0 /= fc; c1 /= fc;
        float ss = c0 * c0 + c1 * c1;
        for (int off = 1; off < 64; off <<= 1) ss += __shfl_xor(ss, off);
        float inv = EXP2_SCALE / fmaxf(sqrtf(ss), 1e-12f);
        ushort2 o;
        o.x = f2bf(c0 * inv); o.y = f2bf(c1 * inv);
        *reinterpret_cast<ushort2*>(cen2 + (size_t)blockIdx.x * DDIM + l * 2) = o;
        if (l == 0) atomicAdd(out2, ss);
    }
}

// K4 v6 body as a device function; REPS=1 -> real kernel, REPS=4 -> probe.
template <int REPS>
__device__ inline void k4_body(
    const unsigned short* __restrict__ xb, const unsigned short* __restrict__ cen,
    const float* __restrict__ nabsG, float* __restrict__ out) {
    extern __shared__ char lds[];
    char* xL0 = lds;
    char* xL1 = lds + 32768;
    float* denP = (float*)(lds + 65536);
    float* wsum = (float*)(lds + 81920);
    int t = threadIdx.x, w = t >> 6, l = t & 63;
    int lm = l & 15, lk = l >> 4;
    float nabs = *nabsG;

    v8bf afr[2][4];
#pragma unroll
    for (int m = 0; m < 2; ++m)
#pragma unroll
        for (int kc = 0; kc < 4; ++kc) {
            int arow = w * 32 + m * 16 + lm;
            afr[m][kc] = *reinterpret_cast<const v8bf*>(cen + (size_t)arow * DDIM + kc * 32 + lk * 8);
        }

    int block0 = blockIdx.x * 1024;
    const char* xbB = (const char*)xb + (size_t)block0 * 256;
    int C0 = w * 128 + l;
    int C1 = C0 + 64;
    int so0 = (C0 >> 4) * 256 + ((((C0 & 15) ^ ((C0 >> 4) & 7))) << 4);
    int so1 = (C1 >> 4) * 256 + ((((C1 & 15) ^ ((C1 >> 4) & 7))) << 4);
    int dw = w * 2048;
    float lossAcc = 0.0f;
    int rs = w * 8 + (l >> 3);
    int rq = (l & 7) * 2;

    for (int rep = 0; rep < REPS; ++rep) {
        if (REPS > 1) __syncthreads();
        GLL16(xbB + so0, xL0 + dw);
        GLL16(xbB + so1, xL0 + dw + 1024);
        asm volatile("s_waitcnt vmcnt(0)" ::: "memory");
        __syncthreads();

        for (int tile = 0; tile < 8; ++tile) {
            char* xc = (tile & 1) ? xL1 : xL0;
            char* xn = (tile & 1) ? xL0 : xL1;
            float* dp = denP + (tile & 1) * 2048;
            if (tile < 7) {
                const char* s = xbB + (size_t)(tile + 1) * 32768;
                GLL16(s + so0, xn + dw);
                GLL16(s + so1, xn + dw + 1024);
            }

#pragma unroll
            for (int h = 0; h < 2; ++h) {
                v4f acc[2][4];
                v4f zero = {0.0f, 0.0f, 0.0f, 0.0f};
#pragma unroll
                for (int m = 0; m < 2; ++m)
#pragma unroll
                    for (int n = 0; n < 4; ++n) acc[m][n] = zero;

#pragma unroll
                for (int kc = 0; kc < 4; ++kc) {
                    int kb = kc * 64 + lk * 16;
                    v8bf b[4];
#pragma unroll
                    for (int n = 0; n < 4; ++n) {
                        int brow = h * 64 + n * 16 + lm;
                        b[n] = *reinterpret_cast<const v8bf*>(xc + brow * 256 + (kb ^ ((brow & 7) << 4)));
                    }
#pragma unroll
                    for (int m = 0; m < 2; ++m)
#pragma unroll
                        for (int n = 0; n < 4; ++n)
                            acc[m][n] = __builtin_amdgcn_mfma_f32_16x16x32_bf16(afr[m][kc], b[n], acc[m][n], 0, 0, 0);
                }

#pragma unroll
                for (int n = 0; n < 4; ++n) {
                    float se = 0.0f;
#pragma unroll
                    for (int m = 0; m < 2; ++m) {
#pragma unroll
                        for (int rr = 0; rr < 4; ++rr)
                            se += __builtin_amdgcn_exp2f(acc[m][n][rr]);
                    }
                    se += __shfl_xor(se, 16); se += __shfl_xor(se, 32);
                    if (l < 16) dp[w * 128 + h * 64 + n * 16 + lm] = se;
                }
            }
            asm volatile("s_waitcnt vmcnt(0)" ::: "memory");
            __syncthreads();
            float den = dp[rq * 128 + rs] + dp[(rq + 1) * 128 + rs];
            den += __shfl_xor(den, 1);
            den += __shfl_xor(den, 2);
            den += __shfl_xor(den, 4);
            if ((l & 7) == 0) lossAcc += __logf(den - nabs);
        }
    }
    lossAcc += __shfl_xor(lossAcc, 8);
    lossAcc += __shfl_xor(lossAcc, 16);
    lossAcc += __shfl_xor(lossAcc, 32);
    if (l == 0) wsum[w] = lossAcc;
    __syncthreads();
    if (t == 0) {
        float s = 0.0f;
#pragma unroll
        for (int q = 0; q < 16; ++q) s += wsum[q];
        atomicAdd(out, s * (1.0f / (NROWS * REPS)));
    }
}

__global__ __launch_bounds__(1024) void k4_loss(
    const unsigned short* __restrict__ xb, const unsigned short* __restrict__ cen,
    const float* __restrict__ nabsG, float* __restrict__ out) {
    k4_body<1>(xb, cen, nabsG, out);
}

__global__ __launch_bounds__(1024) void k4_probe(
    const unsigned short* __restrict__ xb, const unsigned short* __restrict__ cen,
    const float* __restrict__ nabsG, float* __restrict__ out) {
    k4_body<4>(xb, cen, nabsG, out);
}

extern "C" void kernel_launch(void* const* d_in, const int* in_sizes, int n_in,
                              void* d_out, int out_size, void* d_ws, size_t ws_size,
                              hipStream_t stream) {
    const float* in = (const float*)d_in[0];
    const int* tgt = (const int*)d_in[1];
    float* out = (float*)d_out;
    char* ws = (char*)d_ws;
    unsigned short* xb = (unsigned short*)(ws);              // 67108864 B
    int* counts = (int*)(ws + 67108864);                     // 2048 B
    int* offs = (int*)(ws + 67110912);                       // 2048 B
    float* nabsG = (float*)(ws + 67112960);                  // 256 B (pad)
    unsigned short* cen = (unsigned short*)(ws + 67115264);  // 131072 B
    int* ridx = (int*)(ws + 67246336);                       // 1048576 B
    int* bh = (int*)(ws + 68294912);                         // 131072 B
    int* base = (int*)(ws + 68557056);                       // 131072 B
    // probe scratch
    char* pb = ws + 70254592;
    float* out2 = (float*)(pb);                              // 256
    unsigned short* cen2 = (unsigned short*)(pb + 8192);     // 131072

    (void)hipFuncSetAttribute((const void*)k4_loss,
                              hipFuncAttributeMaxDynamicSharedMemorySize, 81984);
    (void)hipFuncSetAttribute((const void*)k4_probe,
                              hipFuncAttributeMaxDynamicSharedMemorySize, 81984);

    // real pipeline
    hipLaunchKernelGGL(k1_normalize, dim3(8192 + NHB), dim3(256), 0, stream, in, tgt, xb, bh);
    hipLaunchKernelGGL(k_prefix, dim3(1), dim3(512), 0, stream, bh, counts, offs, base, nabsG, out);
    hipLaunchKernelGGL(k_scatter, dim3(NHB), dim3(256), 0, stream, tgt, base, ridx);
    hipLaunchKernelGGL(k_centers, dim3(NCLS), dim3(512), 0, stream, xb, ridx, counts, offs, cen, out);
    hipLaunchKernelGGL(k4_loss, dim3(256), dim3(1024), 81984, stream, xb, cen, nabsG, out);

    // amplified probes (x4 work each -> visible in top-5 with counters)
    hipLaunchKernelGGL(cen_probe, dim3(NCLS), dim3(512), 0, stream, xb, ridx, counts, offs, cen2, out2);
    hipLaunchKernelGGL(k4_probe, dim3(256), dim3(1024), 81984, stream, xb, cen, nabsG, out2);
}

// Round 17
// 108.825 us; speedup vs baseline: 2.9549x; 2.9549x over previous
//
#include <hip/hip_runtime.h>
#include <stdint.h>

#define NROWS 262144
#define DDIM 128
#define NCLS 512
#define NHB 64  // hist/scatter blocks
constexpr float INV_BETA = 10.0f;
constexpr float EXP2_SCALE = 14.426950408889634f;  // 10 * log2(e)

typedef __bf16 v8bf __attribute__((ext_vector_type(8)));
typedef float v4f __attribute__((ext_vector_type(4)));

__device__ inline unsigned short f2bf(float f) {
    uint32_t u = __builtin_bit_cast(uint32_t, f);
    u += 0x7FFFu + ((u >> 16) & 1u);
    return (unsigned short)(u >> 16);
}
__device__ inline float bflo(uint32_t u) { return __builtin_bit_cast(float, u << 16); }
__device__ inline float bfhi(uint32_t u) { return __builtin_bit_cast(float, u & 0xFFFF0000u); }

#define GLL16(gsrc, ldst)                                                        \
    __builtin_amdgcn_global_load_lds(                                            \
        (const __attribute__((address_space(1))) void*)(uintptr_t)(gsrc),        \
        (__attribute__((address_space(3))) void*)(uintptr_t)(ldst), 16, 0, 0)

// K1 v5: streaming L2-normalize fp32 -> bf16 (blocks 0..8191); histogram fused.
__global__ __launch_bounds__(256) void k1_normalize(
    const float* __restrict__ in, const int* __restrict__ tgt,
    unsigned short* __restrict__ xb, int* __restrict__ bh) {
    __shared__ int h[NCLS];
    int t = threadIdx.x;
    if (blockIdx.x >= 8192) {
        int b = blockIdx.x - 8192;
        for (int i = t; i < NCLS; i += 256) h[i] = 0;
        __syncthreads();
        int base = b * (NROWS / NHB);
        for (int i = base + t; i < base + NROWS / NHB; i += 256)
            atomicAdd(&h[tgt[i]], 1);
        __syncthreads();
        for (int i = t; i < NCLS; i += 256)
            bh[b * NCLS + i] = h[i];
        return;
    }
    int w = t >> 6;
    int half = (t & 63) >> 5;
    int lane32 = t & 31;
    int hw = blockIdx.x * 8 + w * 2 + half;
    int r0 = hw * 4;
    float4 v[4];
#pragma unroll
    for (int j = 0; j < 4; ++j)
        v[j] = *reinterpret_cast<const float4*>(in + (size_t)(r0 + j) * DDIM + lane32 * 4);
    float s[4];
#pragma unroll
    for (int j = 0; j < 4; ++j)
        s[j] = v[j].x * v[j].x + v[j].y * v[j].y + v[j].z * v[j].z + v[j].w * v[j].w;
#pragma unroll
    for (int off = 1; off < 32; off <<= 1) {
#pragma unroll
        for (int j = 0; j < 4; ++j) s[j] += __shfl_xor(s[j], off);
    }
#pragma unroll
    for (int j = 0; j < 4; ++j) {
        float iv = rsqrtf(fmaxf(s[j], 1e-24f));
        ushort4 o;
        o.x = f2bf(v[j].x * iv); o.y = f2bf(v[j].y * iv);
        o.z = f2bf(v[j].z * iv); o.w = f2bf(v[j].w * iv);
        *reinterpret_cast<ushort4*>(xb + (size_t)(r0 + j) * DDIM + lane32 * 4) = o;
    }
}

__global__ __launch_bounds__(512) void k_prefix(
    const int* __restrict__ bh, int* __restrict__ counts, int* __restrict__ offs,
    int* __restrict__ base, float* __restrict__ nabsG, float* __restrict__ out) {
    __shared__ int sc[NCLS];
    __shared__ int za;
    int t = threadIdx.x;
    int cnt = 0;
#pragma unroll 8
    for (int b = 0; b < NHB; ++b) cnt += bh[b * NCLS + t];
    counts[t] = cnt;
    sc[t] = cnt;
    if (t == 0) za = 0;
    __syncthreads();
    for (int off = 1; off < NCLS; off <<= 1) {
        int v = (t >= off) ? sc[t - off] : 0;
        __syncthreads();
        sc[t] += v;
        __syncthreads();
    }
    int excl = sc[t] - cnt;
    offs[t] = excl;
    if (cnt == 0) atomicAdd(&za, 1);
    int run = excl;
    for (int b = 0; b < NHB; ++b) {
        base[b * NCLS + t] = run;
        run += bh[b * NCLS + t];
    }
    __syncthreads();
    if (t == 0) { *nabsG = (float)za; *out = 0.0f; }
}

__global__ __launch_bounds__(256) void k_scatter(
    const int* __restrict__ tgt, const int* __restrict__ base, int* __restrict__ ridx) {
    __shared__ int cur[NCLS];
    int t = threadIdx.x;
    int b = blockIdx.x;
    cur[t] = base[b * NCLS + t];
    cur[t + 256] = base[b * NCLS + t + 256];
    __syncthreads();
    int r0 = b * (NROWS / NHB);
    for (int i = t; i < NROWS / NHB; i += 256) {
        int row = r0 + i;
        int c = tgt[row];
        int pos = atomicAdd(&cur[c], 1);
        ridx[pos] = row;
    }
}

// centers gather body (MLP 16).
__device__ inline void centers_gather(
    const uint32_t* __restrict__ xb32, const int* __restrict__ ridx,
    int start, int lo, int hi, int l, float& a0, float& a1) {
    int i = lo;
    for (; i + 16 <= hi; i += 16) {
        int id[16]; uint32_t v[16];
#pragma unroll
        for (int j = 0; j < 16; ++j) id[j] = ridx[start + i + j];
#pragma unroll
        for (int j = 0; j < 16; ++j) v[j] = xb32[(size_t)id[j] * 64 + l];
#pragma unroll
        for (int j = 0; j < 16; ++j) { a0 += bflo(v[j]); a1 += bfhi(v[j]); }
    }
    for (; i < hi; ++i) {
        uint32_t v = xb32[(size_t)ridx[start + i] * 64 + l];
        a0 += bflo(v); a1 += bfhi(v);
    }
}

// Per-class mean + L2-normalize -> bf16 centers pre-scaled by 10*log2(e).
__global__ __launch_bounds__(512) void k_centers(
    const unsigned short* __restrict__ xb, const int* __restrict__ ridx,
    const int* __restrict__ counts, const int* __restrict__ offs,
    unsigned short* __restrict__ cen, float* __restrict__ out) {
    __shared__ float2 sP[8][64];
    int t = threadIdx.x, w = t >> 6, l = t & 63;
    int cl = blockIdx.x;
    int cnt = counts[cl], start = offs[cl];
    float a0 = 0.0f, a1 = 0.0f;
    int per = (cnt + 7) >> 3;
    int lo = w * per, hi = min(cnt, lo + per);
    centers_gather((const uint32_t*)xb, ridx, start, lo, hi, l, a0, a1);
    sP[w][l] = make_float2(a0, a1);
    __syncthreads();
    if (w == 0) {
        float c0 = 0.0f, c1 = 0.0f;
#pragma unroll
        for (int q = 0; q < 8; ++q) { c0 += sP[q][l].x; c1 += sP[q][l].y; }
        float fc = fmaxf((float)cnt, 1.0f);
        c0 /= fc; c1 /= fc;
        float ss = c0 * c0 + c1 * c1;
        for (int off = 1; off < 64; off <<= 1) ss += __shfl_xor(ss, off);
        float inv = EXP2_SCALE / fmaxf(sqrtf(ss), 1e-12f);
        ushort2 o;
        o.x = f2bf(c0 * inv); o.y = f2bf(c1 * inv);
        *reinterpret_cast<ushort2*>(cen + (size_t)cl * DDIM + l * 2) = o;
        if (l == 0)
            atomicAdd(out, -(float)cnt * sqrtf(ss) * (INV_BETA / (float)NROWS));
    }
}

// K4 v7: inverted operand roles. 256 blocks x 16 waves. Each wave holds its own
// 64 samples as reg-resident B-frags (loaded once from global); the 128KB
// centers table is staged ONCE per block in LDS (XOR-swizzled, conflict-free)
// and swept over 32 class-tiles with exp2 folded into den[4] per tile.
// Barrier-free main loop; LDS traffic 128KB/wave (was 256KB); acc 16 VGPR.
__global__ __launch_bounds__(1024) void k4_loss(
    const unsigned short* __restrict__ xb, const unsigned short* __restrict__ cen,
    const float* __restrict__ nabsG, float* __restrict__ out) {
    extern __shared__ char lds[];
    char* cenL = lds;                       // 131072
    float* wsum = (float*)(lds + 131072);   // 16 f32
    int t = threadIdx.x, w = t >> 6, l = t & 63;
    int lm = l & 15, lk = l >> 4;
    float nabs = *nabsG;

    // B-frags: wave w owns samples [s0, s0+64). frag (n,kc): sample n*16+lm,
    // dims kc*32 + lk*8 .. +8  (matches mfma B layout: col=l&15, k=(l>>4)*8).
    int s0 = blockIdx.x * 1024 + w * 64;
    const char* xB = (const char*)xb;
    v8bf bfr[4][4];
#pragma unroll
    for (int n = 0; n < 4; ++n)
#pragma unroll
        for (int kc = 0; kc < 4; ++kc)
            bfr[n][kc] = *reinterpret_cast<const v8bf*>(
                xB + (size_t)(s0 + n * 16 + lm) * 256 + kc * 64 + lk * 16);

    // stage centers: 128KB, linear LDS dest + inverse-swizzled global source.
    const char* cB = (const char*)cen;
#pragma unroll
    for (int i = 0; i < 8; ++i) {
        int C = w * 512 + i * 64 + l;
        int src = (C >> 4) * 256 + ((((C & 15) ^ ((C >> 4) & 7))) << 4);
        GLL16(cB + src, cenL + w * 8192 + i * 1024);
    }
    asm volatile("s_waitcnt vmcnt(0)" ::: "memory");
    __syncthreads();

    float den[4] = {0.0f, 0.0f, 0.0f, 0.0f};
    for (int m = 0; m < 32; ++m) {
        v8bf a[4];
#pragma unroll
        for (int kc = 0; kc < 4; ++kc) {
            int row = m * 16 + lm;
            a[kc] = *reinterpret_cast<const v8bf*>(
                cenL + row * 256 + ((kc * 64 + lk * 16) ^ ((row & 7) << 4)));
        }
        v4f acc[4];
        v4f zero = {0.0f, 0.0f, 0.0f, 0.0f};
#pragma unroll
        for (int n = 0; n < 4; ++n) acc[n] = zero;
#pragma unroll
        for (int kc = 0; kc < 4; ++kc)
#pragma unroll
            for (int n = 0; n < 4; ++n)
                acc[n] = __builtin_amdgcn_mfma_f32_16x16x32_bf16(a[kc], bfr[n][kc], acc[n], 0, 0, 0);
#pragma unroll
        for (int n = 0; n < 4; ++n)
#pragma unroll
            for (int rr = 0; rr < 4; ++rr)
                den[n] += __builtin_amdgcn_exp2f(acc[n][rr]);
    }

    // den[n]: lanes {lm, lm+16, lm+32, lm+48} hold class-row partials for
    // sample n*16+lm -> 2 shuffles finalize.
    float lossAcc = 0.0f;
#pragma unroll
    for (int n = 0; n < 4; ++n) {
        float d = den[n];
        d += __shfl_xor(d, 16);
        d += __shfl_xor(d, 32);
        if (l < 16) lossAcc += __logf(d - nabs);
    }
#pragma unroll
    for (int off = 1; off < 64; off <<= 1) lossAcc += __shfl_xor(lossAcc, off);
    if (l == 0) wsum[w] = lossAcc;
    __syncthreads();
    if (t == 0) {
        float s = 0.0f;
#pragma unroll
        for (int q = 0; q < 16; ++q) s += wsum[q];
        atomicAdd(out, s * (1.0f / NROWS));
    }
}

extern "C" void kernel_launch(void* const* d_in, const int* in_sizes, int n_in,
                              void* d_out, int out_size, void* d_ws, size_t ws_size,
                              hipStream_t stream) {
    const float* in = (const float*)d_in[0];
    const int* tgt = (const int*)d_in[1];
    float* out = (float*)d_out;
    char* ws = (char*)d_ws;
    unsigned short* xb = (unsigned short*)(ws);              // 67108864 B
    int* counts = (int*)(ws + 67108864);                     // 2048 B
    int* offs = (int*)(ws + 67110912);                       // 2048 B
    float* nabsG = (float*)(ws + 67112960);                  // 256 B (pad)
    unsigned short* cen = (unsigned short*)(ws + 67115264);  // 131072 B
    int* ridx = (int*)(ws + 67246336);                       // 1048576 B
    int* bh = (int*)(ws + 68294912);                         // 131072 B
    int* base = (int*)(ws + 68557056);                       // 131072 B

    (void)hipFuncSetAttribute((const void*)k4_loss,
                              hipFuncAttributeMaxDynamicSharedMemorySize, 131136);

    hipLaunchKernelGGL(k1_normalize, dim3(8192 + NHB), dim3(256), 0, stream, in, tgt, xb, bh);
    hipLaunchKernelGGL(k_prefix, dim3(1), dim3(512), 0, stream, bh, counts, offs, base, nabsG, out);
    hipLaunchKernelGGL(k_scatter, dim3(NHB), dim3(256), 0, stream, tgt, base, ridx);
    hipLaunchKernelGGL(k_centers, dim3(NCLS), dim3(512), 0, stream, xb, ridx, counts, offs, cen, out);
    hipLaunchKernelGGL(k4_loss, dim3(256), dim3(1024), 131136, stream, xb, cen, nabsG, out);
}